// Round 1
// baseline (1999.524 us; speedup 1.0000x reference)
//
#include <hip/hip_runtime.h>

#define N_NODES 100000
#define E_EDGES 3200000
#define CH_IN   256
#define HD      64
#define NG      512
#define BN_EPS  1e-5f

// ---------------- init: deg=1 (self loops), zero stats/pool ----------------
__global__ __launch_bounds__(256) void k_init(float* __restrict__ deg,
                                              float* __restrict__ stats1,
                                              float* __restrict__ stats2,
                                              float* __restrict__ sums,
                                              float* __restrict__ cnt) {
  int i = blockIdx.x * 256 + threadIdx.x;
  if (i < N_NODES) deg[i] = 1.0f;
  if (i < 128) { stats1[i] = 0.f; stats2[i] = 0.f; }
  if (i < NG * HD) sums[i] = 0.f;
  if (i < NG) cnt[i] = 0.f;
}

// ---------------- degree accumulation over edge dst ----------------
__global__ __launch_bounds__(256) void k_deg(const int* __restrict__ ei, float* __restrict__ deg) {
  int e = blockIdx.x * 256 + threadIdx.x;
  if (e < E_EDGES) atomicAdd(&deg[ei[E_EDGES + e]], 1.0f);
}

__global__ __launch_bounds__(256) void k_dis(float* __restrict__ deg) {
  int i = blockIdx.x * 256 + threadIdx.x;
  if (i < N_NODES) deg[i] = rsqrtf(deg[i]);  // deg >= 1 always (self loop)
}

// ---------------- GEMM: y[n][h] = dis[n] * sum_c in[n][c]*W[c][h]; also acc=y ----
// block = 256 threads, 32 nodes per block. thread t: h = t&63, w = t>>6, rows w+4j.
template <int K>
__global__ __launch_bounds__(256) void k_gemm(const float* __restrict__ in,
                                              const float* __restrict__ W,
                                              const float* __restrict__ dis,
                                              float* __restrict__ y,
                                              float* __restrict__ acc) {
  __shared__ float xs[32 * K];
  const int tid = threadIdx.x;
  const int n0 = blockIdx.x * 32;
  const float4* in4 = (const float4*)(in + (size_t)n0 * K);
  float4* xs4 = (float4*)xs;
#pragma unroll
  for (int i = 0; i < (32 * K / 4) / 256; ++i) xs4[tid + i * 256] = in4[tid + i * 256];
  __syncthreads();

  const int h = tid & 63, w = tid >> 6;
  float a[8] = {0, 0, 0, 0, 0, 0, 0, 0};
  for (int c = 0; c < K; c += 4) {
    const float w0 = W[(c + 0) * 64 + h];
    const float w1v = W[(c + 1) * 64 + h];
    const float w2v = W[(c + 2) * 64 + h];
    const float w3v = W[(c + 3) * 64 + h];
#pragma unroll
    for (int j = 0; j < 8; ++j) {
      const float4 xv = *(const float4*)&xs[(w + 4 * j) * K + c];
      a[j] = fmaf(xv.x, w0, fmaf(xv.y, w1v, fmaf(xv.z, w2v, fmaf(xv.w, w3v, a[j]))));
    }
  }
#pragma unroll
  for (int j = 0; j < 8; ++j) {
    const int n = n0 + w + 4 * j;
    const float v = dis[n] * a[j];
    y[(size_t)n * 64 + h] = v;
    acc[(size_t)n * 64 + h] = v;
  }
}

// ---------------- edge scatter: acc[dst] += y[src], wave per edge ----------------
__global__ __launch_bounds__(256) void k_scatter(const int* __restrict__ ei,
                                                 const float* __restrict__ y,
                                                 float* __restrict__ acc) {
  const int lane = threadIdx.x & 63;
  const int wid = (blockIdx.x * 256 + threadIdx.x) >> 6;
  const int nw = (gridDim.x * 256) >> 6;
  for (int e = wid; e < E_EDGES; e += nw) {
    const int s = ei[e];
    const int d = ei[E_EDGES + e];
    atomicAdd(&acc[(size_t)d * 64 + lane], y[(size_t)s * 64 + lane]);
  }
}

// ---------------- conv epilogue: relu(dis*acc + b), accumulate BN stats ----------------
__global__ __launch_bounds__(256) void k_finish(const float* __restrict__ acc,
                                                const float* __restrict__ dis,
                                                const float* __restrict__ bias,
                                                float* __restrict__ hout,
                                                float* __restrict__ stats) {
  const int tid = threadIdx.x;
  const int h = tid & 63, w = tid >> 6;
  const int n0 = blockIdx.x * 128;
  const float b = bias[h];
  float s1 = 0.f, s2 = 0.f;
  for (int r = w; r < 128; r += 4) {
    const int n = n0 + r;
    if (n >= N_NODES) break;
    float v = dis[n] * acc[(size_t)n * 64 + h] + b;
    v = fmaxf(v, 0.f);
    hout[(size_t)n * 64 + h] = v;
    s1 += v;
    s2 += v * v;
  }
  __shared__ float r1[256], r2[256];
  r1[tid] = s1;
  r2[tid] = s2;
  __syncthreads();
  if (tid < 64) {
    atomicAdd(&stats[tid], r1[tid] + r1[tid + 64] + r1[tid + 128] + r1[tid + 192]);
  } else if (tid < 128) {
    const int hh = tid - 64;
    atomicAdd(&stats[64 + hh], r2[hh] + r2[hh + 64] + r2[hh + 128] + r2[hh + 192]);
  }
}

// ---------------- BN affine apply ----------------
__global__ __launch_bounds__(256) void k_bn(const float* __restrict__ hin,
                                            const float* __restrict__ stats,
                                            const float* __restrict__ gam,
                                            const float* __restrict__ bet,
                                            float* __restrict__ hout) {
  const size_t i = (size_t)blockIdx.x * 256 + threadIdx.x;
  if (i >= (size_t)N_NODES * 64) return;
  const int h = (int)(i & 63);
  const float m = stats[h] * (1.0f / N_NODES);
  const float v = stats[64 + h] * (1.0f / N_NODES) - m * m;
  const float sc = rsqrtf(v + BN_EPS) * gam[h];
  const float sh = bet[h] - m * sc;
  hout[i] = hin[i] * sc + sh;
}

// ---------------- fused BN2 + mean-pool accumulation ----------------
__global__ __launch_bounds__(256) void k_pool(const float* __restrict__ hin,
                                              const float* __restrict__ stats,
                                              const float* __restrict__ gam,
                                              const float* __restrict__ bet,
                                              const int* __restrict__ batch,
                                              float* __restrict__ sums,
                                              float* __restrict__ cnt) {
  const int lane = threadIdx.x & 63;
  const int wid = (blockIdx.x * 256 + threadIdx.x) >> 6;
  const int nw = (gridDim.x * 256) >> 6;
  const float m = stats[lane] * (1.0f / N_NODES);
  const float v = stats[64 + lane] * (1.0f / N_NODES) - m * m;
  const float sc = rsqrtf(v + BN_EPS) * gam[lane];
  const float sh = bet[lane] - m * sc;
  for (int n = wid; n < N_NODES; n += nw) {
    const int b = batch[n];
    const float val = hin[(size_t)n * 64 + lane] * sc + sh;
    atomicAdd(&sums[b * 64 + lane], val);
    if (lane == 0) atomicAdd(&cnt[b], 1.0f);
  }
}

// ---------------- fused 5-layer MLP head, one block per graph ----------------
__global__ __launch_bounds__(128) void k_mlp(const float* __restrict__ sums,
                                             const float* __restrict__ cnt,
                                             const float* __restrict__ fw1, const float* __restrict__ fb1,
                                             const float* __restrict__ fw2, const float* __restrict__ fb2,
                                             const float* __restrict__ fw3, const float* __restrict__ fb3,
                                             const float* __restrict__ fw4, const float* __restrict__ fb4,
                                             const float* __restrict__ ow, const float* __restrict__ ob,
                                             float* __restrict__ out) {
  __shared__ float u0[128], u1[128];
  const int g = blockIdx.x, t = threadIdx.x;
  if (t < 64) u0[t] = sums[g * 64 + t] / fmaxf(cnt[g], 1.0f);
  __syncthreads();
  if (t < 128) {  // 64 -> 128
    float a = fb1[t];
    for (int k = 0; k < 64; ++k) a = fmaf(u0[k], fw1[k * 128 + t], a);
    u1[t] = fmaxf(a, 0.f);
  }
  __syncthreads();
  if (t < 64) {  // 128 -> 64
    float a = fb2[t];
    for (int k = 0; k < 128; ++k) a = fmaf(u1[k], fw2[k * 64 + t], a);
    u0[t] = fmaxf(a, 0.f);
  }
  __syncthreads();
  if (t < 32) {  // 64 -> 32
    float a = fb3[t];
    for (int k = 0; k < 64; ++k) a = fmaf(u0[k], fw3[k * 32 + t], a);
    u1[t] = fmaxf(a, 0.f);
  }
  __syncthreads();
  if (t < 16) {  // 32 -> 16
    float a = fb4[t];
    for (int k = 0; k < 32; ++k) a = fmaf(u1[k], fw4[k * 16 + t], a);
    u0[t] = fmaxf(a, 0.f);
  }
  __syncthreads();
  if (t < 2) {  // 16 -> 2
    float a = ob[t];
    for (int k = 0; k < 16; ++k) a = fmaf(u0[k], ow[k * 2 + t], a);
    out[g * 2 + t] = a;
  }
}

extern "C" void kernel_launch(void* const* d_in, const int* in_sizes, int n_in,
                              void* d_out, int out_size, void* d_ws, size_t ws_size,
                              hipStream_t stream) {
  const float* x    = (const float*)d_in[0];
  const int*   ei   = (const int*)d_in[1];
  const int*   batch= (const int*)d_in[2];
  const float* w1   = (const float*)d_in[3];
  const float* b1   = (const float*)d_in[4];
  const float* w2   = (const float*)d_in[5];
  const float* b2   = (const float*)d_in[6];
  const float* g1   = (const float*)d_in[7];
  const float* be1  = (const float*)d_in[8];
  const float* g2   = (const float*)d_in[9];
  const float* be2  = (const float*)d_in[10];
  const float* fw1  = (const float*)d_in[11]; const float* fb1 = (const float*)d_in[12];
  const float* fw2  = (const float*)d_in[13]; const float* fb2 = (const float*)d_in[14];
  const float* fw3  = (const float*)d_in[15]; const float* fb3 = (const float*)d_in[16];
  const float* fw4  = (const float*)d_in[17]; const float* fb4 = (const float*)d_in[18];
  const float* ow   = (const float*)d_in[19]; const float* ob  = (const float*)d_in[20];
  float* out = (float*)d_out;

  char* ws = (char*)d_ws;
  float* dis  = (float*)ws; ws += (((size_t)N_NODES * 4 + 255) & ~(size_t)255);
  float* bufA = (float*)ws; ws += (size_t)N_NODES * 64 * 4;
  float* bufB = (float*)ws; ws += (size_t)N_NODES * 64 * 4;
  float* bufC = (float*)ws; ws += (size_t)N_NODES * 64 * 4;
  float* stats1 = (float*)ws; ws += 512;
  float* stats2 = (float*)ws; ws += 512;
  float* sums   = (float*)ws; ws += (size_t)NG * 64 * 4;
  float* cnt    = (float*)ws; ws += (size_t)NG * 4;

  // degree -> dis
  k_init<<<(N_NODES + 255) / 256, 256, 0, stream>>>(dis, stats1, stats2, sums, cnt);
  k_deg<<<(E_EDGES + 255) / 256, 256, 0, stream>>>(ei, dis);
  k_dis<<<(N_NODES + 255) / 256, 256, 0, stream>>>(dis);

  // conv1: y = dis*(x@w1) -> bufA; acc(self-loop) -> bufB
  k_gemm<256><<<N_NODES / 32, 256, 0, stream>>>(x, w1, dis, bufA, bufB);
  k_scatter<<<2048, 256, 0, stream>>>(ei, bufA, bufB);
  k_finish<<<(N_NODES + 127) / 128, 256, 0, stream>>>(bufB, dis, b1, bufC, stats1);
  k_bn<<<(int)(((size_t)N_NODES * 64 + 255) / 256), 256, 0, stream>>>(bufC, stats1, g1, be1, bufA);

  // conv2: y = dis*(h1n@w2) -> bufC; acc -> bufB
  k_gemm<64><<<N_NODES / 32, 256, 0, stream>>>(bufA, w2, dis, bufC, bufB);
  k_scatter<<<2048, 256, 0, stream>>>(ei, bufC, bufB);
  k_finish<<<(N_NODES + 127) / 128, 256, 0, stream>>>(bufB, dis, b2, bufA, stats2);

  // BN2 + pool + MLP head
  k_pool<<<2048, 256, 0, stream>>>(bufA, stats2, g2, be2, batch, sums, cnt);
  k_mlp<<<NG, 128, 0, stream>>>(sums, cnt, fw1, fb1, fw2, fb2, fw3, fb3, fw4, fb4, ow, ob, out);
}

// Round 2
// 1002.639 us; speedup vs baseline: 1.9943x; 1.9943x over previous
//
#include <hip/hip_runtime.h>

#define N_NODES 100000
#define E_EDGES 3200000
#define CH_IN   256
#define HD      64
#define NG      512
#define BN_EPS  1e-5f

// ---------------- zero: int hist, stats, pool sums/cnt ----------------
__global__ __launch_bounds__(256) void k_zero(int* __restrict__ cnt_i,
                                              float* __restrict__ stats1,
                                              float* __restrict__ stats2,
                                              float* __restrict__ sums,
                                              float* __restrict__ cnt) {
  int i = blockIdx.x * 256 + threadIdx.x;
  if (i < N_NODES) cnt_i[i] = 0;
  if (i < 128) { stats1[i] = 0.f; stats2[i] = 0.f; }
  if (i < NG * HD) sums[i] = 0.f;
  if (i < NG) cnt[i] = 0.f;
}

// ---------------- histogram of dst ----------------
__global__ __launch_bounds__(256) void k_hist(const int* __restrict__ ei, int* __restrict__ cnt_i) {
  int e = blockIdx.x * 256 + threadIdx.x;
  if (e < E_EDGES) atomicAdd(&cnt_i[ei[E_EDGES + e]], 1);
}

// ---------------- scan step 1: per-block exclusive scan + block totals ----------------
__global__ __launch_bounds__(256) void k_scan1(const int* __restrict__ cnt_i,
                                               int* __restrict__ row_ex,
                                               int* __restrict__ partials) {
  __shared__ int sm[256];
  const int tid = threadIdx.x;
  const int i = blockIdx.x * 256 + tid;
  int c = (i < N_NODES) ? cnt_i[i] : 0;
  int val = c;
  sm[tid] = val;
  __syncthreads();
  for (int off = 1; off < 256; off <<= 1) {
    int t = (tid >= off) ? sm[tid - off] : 0;
    __syncthreads();
    val += t;
    sm[tid] = val;
    __syncthreads();
  }
  if (i < N_NODES) row_ex[i] = val - c;
  if (tid == 255) partials[blockIdx.x] = val;
}

// ---------------- scan step 2: exclusive scan of block totals (one block) ----------------
__global__ __launch_bounds__(512) void k_scan2(int* __restrict__ partials, int nb) {
  __shared__ int sm[512];
  const int tid = threadIdx.x;
  int c = (tid < nb) ? partials[tid] : 0;
  int val = c;
  sm[tid] = val;
  __syncthreads();
  for (int off = 1; off < 512; off <<= 1) {
    int t = (tid >= off) ? sm[tid - off] : 0;
    __syncthreads();
    val += t;
    sm[tid] = val;
    __syncthreads();
  }
  if (tid < nb) partials[tid] = val - c;
}

// ---------------- scan step 3: row_start, cursor, dis ----------------
__global__ __launch_bounds__(256) void k_scan3(const int* __restrict__ cnt_i,
                                               const int* __restrict__ row_ex,
                                               const int* __restrict__ partials,
                                               int* __restrict__ row_start,
                                               int* __restrict__ cursor,
                                               float* __restrict__ dis) {
  const int i = blockIdx.x * 256 + threadIdx.x;
  if (i < N_NODES) {
    const int rs = row_ex[i] + partials[i >> 8];
    row_start[i] = rs;
    cursor[i] = rs;
    dis[i] = rsqrtf((float)(cnt_i[i] + 1));  // +1 self loop
  }
  if (i == 0) row_start[N_NODES] = E_EDGES;
}

// ---------------- counting-sort fill: csr_src grouped by dst ----------------
__global__ __launch_bounds__(256) void k_fill(const int* __restrict__ ei,
                                              int* __restrict__ cursor,
                                              int* __restrict__ csr) {
  const int e = blockIdx.x * 256 + threadIdx.x;
  if (e < E_EDGES) {
    const int d = ei[E_EDGES + e];
    const int pos = atomicAdd(&cursor[d], 1);
    csr[pos] = ei[e];
  }
}

// ---------------- GEMM: y[n][h] = dis[n] * sum_c in'[n][c]*W[c][h] ----------------
// in' = BN-affine(in) when BN (uses stats/gam/bet); block=256, 32 nodes/block.
template <int K, bool BN>
__global__ __launch_bounds__(256) void k_gemm(const float* __restrict__ in,
                                              const float* __restrict__ W,
                                              const float* __restrict__ dis,
                                              const float* __restrict__ stats,
                                              const float* __restrict__ gam,
                                              const float* __restrict__ bet,
                                              float* __restrict__ y) {
  __shared__ float xs[32 * K];
  __shared__ float scv[64], shv[64];
  const int tid = threadIdx.x;
  const int n0 = blockIdx.x * 32;
  if (BN) {
    if (tid < 64) {
      const float m = stats[tid] * (1.0f / N_NODES);
      const float v = stats[64 + tid] * (1.0f / N_NODES) - m * m;
      const float sc = rsqrtf(v + BN_EPS) * gam[tid];
      scv[tid] = sc;
      shv[tid] = bet[tid] - m * sc;
    }
    __syncthreads();
  }
  const float4* in4 = (const float4*)(in + (size_t)n0 * K);
  float4* xs4 = (float4*)xs;
#pragma unroll
  for (int i = 0; i < (32 * K / 4) / 256; ++i) {
    float4 v = in4[tid + i * 256];
    if (BN) {
      const int c = ((tid + i * 256) * 4) & (K - 1);
      v.x = v.x * scv[c] + shv[c];
      v.y = v.y * scv[c + 1] + shv[c + 1];
      v.z = v.z * scv[c + 2] + shv[c + 2];
      v.w = v.w * scv[c + 3] + shv[c + 3];
    }
    xs4[tid + i * 256] = v;
  }
  __syncthreads();

  const int h = tid & 63, w = tid >> 6;
  float a[8] = {0, 0, 0, 0, 0, 0, 0, 0};
  for (int c = 0; c < K; c += 4) {
    const float w0 = W[(c + 0) * 64 + h];
    const float w1v = W[(c + 1) * 64 + h];
    const float w2v = W[(c + 2) * 64 + h];
    const float w3v = W[(c + 3) * 64 + h];
#pragma unroll
    for (int j = 0; j < 8; ++j) {
      const float4 xv = *(const float4*)&xs[(w + 4 * j) * K + c];
      a[j] = fmaf(xv.x, w0, fmaf(xv.y, w1v, fmaf(xv.z, w2v, fmaf(xv.w, w3v, a[j]))));
    }
  }
#pragma unroll
  for (int j = 0; j < 8; ++j) {
    const int n = n0 + w + 4 * j;
    y[(size_t)n * 64 + h] = dis[n] * a[j];
  }
}

// ---------------- gather + conv epilogue: h = relu(dis*(y[n]+sum y[src]) + b), BN stats ----
__global__ __launch_bounds__(256) void k_gather(const int* __restrict__ csr,
                                                const int* __restrict__ rs,
                                                const float* __restrict__ y,
                                                const float* __restrict__ dis,
                                                const float* __restrict__ bias,
                                                float* __restrict__ hout,
                                                float* __restrict__ stats) {
  const int tid = threadIdx.x;
  const int lane = tid & 63;
  const int wid = (blockIdx.x * 256 + tid) >> 6;
  const int nw = (gridDim.x * 256) >> 6;
  const int per = (N_NODES + nw - 1) / nw;
  const int n0 = wid * per;
  const int n1 = min(N_NODES, n0 + per);
  const float b = bias[lane];
  float s1 = 0.f, s2 = 0.f;
  for (int n = n0; n < n1; ++n) {
    int e = rs[n];
    const int end = rs[n + 1];
    float a = y[(size_t)n * 64 + lane];
    float a2 = 0.f;
    for (; e + 4 <= end; e += 4) {
      const int i0 = csr[e], i1 = csr[e + 1], i2 = csr[e + 2], i3 = csr[e + 3];
      const float v0 = y[(size_t)i0 * 64 + lane];
      const float v1 = y[(size_t)i1 * 64 + lane];
      const float v2 = y[(size_t)i2 * 64 + lane];
      const float v3 = y[(size_t)i3 * 64 + lane];
      a += v0 + v1;
      a2 += v2 + v3;
    }
    for (; e < end; ++e) a += y[(size_t)csr[e] * 64 + lane];
    float v = fmaxf(dis[n] * (a + a2) + b, 0.f);
    hout[(size_t)n * 64 + lane] = v;
    s1 += v;
    s2 += v * v;
  }
  __shared__ float r1[256], r2[256];
  r1[tid] = s1;
  r2[tid] = s2;
  __syncthreads();
  if (tid < 64) {
    atomicAdd(&stats[tid], r1[tid] + r1[tid + 64] + r1[tid + 128] + r1[tid + 192]);
  } else if (tid < 128) {
    const int h = tid - 64;
    atomicAdd(&stats[64 + h], r2[h] + r2[h + 64] + r2[h + 128] + r2[h + 192]);
  }
}

// ---------------- BN2 + mean-pool, run-length over sorted batch ----------------
__global__ __launch_bounds__(256) void k_pool(const float* __restrict__ hin,
                                              const float* __restrict__ stats,
                                              const float* __restrict__ gam,
                                              const float* __restrict__ bet,
                                              const int* __restrict__ batch,
                                              float* __restrict__ sums,
                                              float* __restrict__ cnt) {
  const int lane = threadIdx.x & 63;
  const int wid = (blockIdx.x * 256 + threadIdx.x) >> 6;
  const int nw = (gridDim.x * 256) >> 6;
  const int per = (N_NODES + nw - 1) / nw;
  const int n0 = wid * per;
  const int n1 = min(N_NODES, n0 + per);
  const float m = stats[lane] * (1.0f / N_NODES);
  const float v = stats[64 + lane] * (1.0f / N_NODES) - m * m;
  const float sc = rsqrtf(v + BN_EPS) * gam[lane];
  const float sh = bet[lane] - m * sc;
  int cur = -1, run = 0;
  float a = 0.f;
  for (int n = n0; n < n1; ++n) {
    const int b = batch[n];
    if (b != cur) {
      if (run) {
        atomicAdd(&sums[cur * 64 + lane], a);
        if (lane == 0) atomicAdd(&cnt[cur], (float)run);
      }
      cur = b; run = 0; a = 0.f;
    }
    a += hin[(size_t)n * 64 + lane] * sc + sh;
    ++run;
  }
  if (run) {
    atomicAdd(&sums[cur * 64 + lane], a);
    if (lane == 0) atomicAdd(&cnt[cur], (float)run);
  }
}

// ---------------- fused 5-layer MLP head, one block per graph ----------------
__global__ __launch_bounds__(128) void k_mlp(const float* __restrict__ sums,
                                             const float* __restrict__ cnt,
                                             const float* __restrict__ fw1, const float* __restrict__ fb1,
                                             const float* __restrict__ fw2, const float* __restrict__ fb2,
                                             const float* __restrict__ fw3, const float* __restrict__ fb3,
                                             const float* __restrict__ fw4, const float* __restrict__ fb4,
                                             const float* __restrict__ ow, const float* __restrict__ ob,
                                             float* __restrict__ out) {
  __shared__ float u0[128], u1[128];
  const int g = blockIdx.x, t = threadIdx.x;
  if (t < 64) u0[t] = sums[g * 64 + t] / fmaxf(cnt[g], 1.0f);
  __syncthreads();
  if (t < 128) {
    float a = fb1[t];
    for (int k = 0; k < 64; ++k) a = fmaf(u0[k], fw1[k * 128 + t], a);
    u1[t] = fmaxf(a, 0.f);
  }
  __syncthreads();
  if (t < 64) {
    float a = fb2[t];
    for (int k = 0; k < 128; ++k) a = fmaf(u1[k], fw2[k * 64 + t], a);
    u0[t] = fmaxf(a, 0.f);
  }
  __syncthreads();
  if (t < 32) {
    float a = fb3[t];
    for (int k = 0; k < 64; ++k) a = fmaf(u0[k], fw3[k * 32 + t], a);
    u1[t] = fmaxf(a, 0.f);
  }
  __syncthreads();
  if (t < 16) {
    float a = fb4[t];
    for (int k = 0; k < 32; ++k) a = fmaf(u1[k], fw4[k * 16 + t], a);
    u0[t] = fmaxf(a, 0.f);
  }
  __syncthreads();
  if (t < 2) {
    float a = ob[t];
    for (int k = 0; k < 16; ++k) a = fmaf(u0[k], ow[k * 2 + t], a);
    out[g * 2 + t] = a;
  }
}

extern "C" void kernel_launch(void* const* d_in, const int* in_sizes, int n_in,
                              void* d_out, int out_size, void* d_ws, size_t ws_size,
                              hipStream_t stream) {
  const float* x    = (const float*)d_in[0];
  const int*   ei   = (const int*)d_in[1];
  const int*   batch= (const int*)d_in[2];
  const float* w1   = (const float*)d_in[3];
  const float* b1   = (const float*)d_in[4];
  const float* w2   = (const float*)d_in[5];
  const float* b2   = (const float*)d_in[6];
  const float* g1   = (const float*)d_in[7];
  const float* be1  = (const float*)d_in[8];
  const float* g2   = (const float*)d_in[9];
  const float* be2  = (const float*)d_in[10];
  const float* fw1  = (const float*)d_in[11]; const float* fb1 = (const float*)d_in[12];
  const float* fw2  = (const float*)d_in[13]; const float* fb2 = (const float*)d_in[14];
  const float* fw3  = (const float*)d_in[15]; const float* fb3 = (const float*)d_in[16];
  const float* fw4  = (const float*)d_in[17]; const float* fb4 = (const float*)d_in[18];
  const float* ow   = (const float*)d_in[19]; const float* ob  = (const float*)d_in[20];
  float* out = (float*)d_out;

  char* ws = (char*)d_ws;
  auto alloc = [&](size_t bytes) {
    void* p = ws;
    ws += (bytes + 255) & ~(size_t)255;
    return p;
  };
  float* dis      = (float*)alloc((size_t)N_NODES * 4);
  int*   cnt_i    = (int*)  alloc((size_t)N_NODES * 4);
  int*   row_ex   = (int*)  alloc((size_t)N_NODES * 4);
  int*   row_start= (int*)  alloc((size_t)(N_NODES + 1) * 4);
  int*   cursor   = (int*)  alloc((size_t)N_NODES * 4);
  int*   partials = (int*)  alloc(512 * 4);
  int*   csr      = (int*)  alloc((size_t)E_EDGES * 4);
  float* bufA     = (float*)alloc((size_t)N_NODES * 64 * 4);
  float* bufB     = (float*)alloc((size_t)N_NODES * 64 * 4);
  float* bufC     = (float*)alloc((size_t)N_NODES * 64 * 4);
  float* stats1   = (float*)alloc(512);
  float* stats2   = (float*)alloc(512);
  float* sums     = (float*)alloc((size_t)NG * 64 * 4);
  float* cnt      = (float*)alloc((size_t)NG * 4);

  const int nblkN = (N_NODES + 255) / 256;   // 391
  const int nblkE = (E_EDGES + 255) / 256;   // 12500

  // CSR build (shared by both conv layers) + dis
  k_zero <<<nblkN, 256, 0, stream>>>(cnt_i, stats1, stats2, sums, cnt);
  k_hist <<<nblkE, 256, 0, stream>>>(ei, cnt_i);
  k_scan1<<<nblkN, 256, 0, stream>>>(cnt_i, row_ex, partials);
  k_scan2<<<1, 512, 0, stream>>>(partials, nblkN);
  k_scan3<<<nblkN, 256, 0, stream>>>(cnt_i, row_ex, partials, row_start, cursor, dis);
  k_fill <<<nblkE, 256, 0, stream>>>(ei, cursor, csr);

  // conv1: y1 = dis*(x@w1) -> bufA; gather -> h1raw=bufB + stats1
  k_gemm<256, false><<<N_NODES / 32, 256, 0, stream>>>(x, w1, dis, nullptr, nullptr, nullptr, bufA);
  k_gather<<<2048, 256, 0, stream>>>(csr, row_start, bufA, dis, b1, bufB, stats1);

  // conv2: y2 = dis*(BN1(h1raw)@w2) -> bufC; gather -> h2raw=bufA + stats2
  k_gemm<64, true><<<N_NODES / 32, 256, 0, stream>>>(bufB, w2, dis, stats1, g1, be1, bufC);
  k_gather<<<2048, 256, 0, stream>>>(csr, row_start, bufC, dis, b2, bufA, stats2);

  // BN2 + pool (sorted batch, run-length) + MLP head
  k_pool<<<512, 256, 0, stream>>>(bufA, stats2, g2, be2, batch, sums, cnt);
  k_mlp <<<NG, 128, 0, stream>>>(sums, cnt, fw1, fb1, fw2, fb2, fw3, fb3, fw4, fb4, ow, ob, out);
}